// Round 3
// baseline (462.579 us; speedup 1.0000x reference)
//
#include <hip/hip_runtime.h>
#include <math.h>

#define ND 100000
#define DD 64
#define LN_EPS 1e-5f

// ---------------- Kernel A: projections qk = x@qk_w^T + qk_b ; v = x@v_w^T + v_b
__global__ __launch_bounds__(256) void proj_kernel(
    const float* __restrict__ x,
    const float* __restrict__ qk_w, const float* __restrict__ qk_b,
    const float* __restrict__ v_w,  const float* __restrict__ v_b,
    float* __restrict__ qk, float* __restrict__ v, int n)
{
    __shared__ float lqw[64 * 65];
    __shared__ float lvw[64 * 65];
    __shared__ float lx[4][64];
    int tid = threadIdx.x;
    for (int i = tid; i < 64 * 64; i += 256) {
        int r = i >> 6, c = i & 63;
        lqw[r * 65 + c] = qk_w[i];
        lvw[r * 65 + c] = v_w[i];
    }
    int wave = tid >> 6, lane = tid & 63;
    int node = blockIdx.x * 4 + wave;
    float xv = 0.f;
    if (node < n) xv = x[node * 64 + lane];
    lx[wave][lane] = xv;
    __syncthreads();
    float accq = 0.f, accv = 0.f;
    #pragma unroll
    for (int j = 0; j < 64; ++j) {
        float xb = lx[wave][j];                 // LDS broadcast (free)
        accq = fmaf(xb, lqw[lane * 65 + j], accq);
        accv = fmaf(xb, lvw[lane * 65 + j], accv);
    }
    if (node < n) {
        qk[node * 64 + lane] = accq + qk_b[lane];
        v [node * 64 + lane] = accv + v_b[lane];
    }
}

// ---------------- Kernel B: in-degree histogram
__global__ void hist_kernel(const int* __restrict__ dst, int* __restrict__ deg, int E)
{
    int i = blockIdx.x * blockDim.x + threadIdx.x;
    if (i < E) atomicAdd(&deg[dst[i]], 1);
}

// ---------------- Kernel C1: per-block exclusive scan of deg (256 elems/block)
__global__ __launch_bounds__(256) void scan1_kernel(
    const int* __restrict__ deg, int* __restrict__ offs, int* __restrict__ bsum, int n)
{
    __shared__ int tmp[256];
    int t = threadIdx.x;
    int i = blockIdx.x * 256 + t;
    int v = (i < n) ? deg[i] : 0;
    tmp[t] = v;
    __syncthreads();
    int val = v;
    for (int off = 1; off < 256; off <<= 1) {
        int add = (t >= off) ? tmp[t - off] : 0;
        __syncthreads();
        val += add;
        tmp[t] = val;
        __syncthreads();
    }
    if (i < n) offs[i] = val - v;      // exclusive within block
    if (t == 255) bsum[blockIdx.x] = val;
}

// ---------------- Kernel C2: scan of block sums (single block, nb <= 512)
__global__ __launch_bounds__(512) void scan2_kernel(
    const int* __restrict__ bsum, int* __restrict__ bscan, int nb)
{
    __shared__ int tmp[512];
    int t = threadIdx.x;
    int v = (t < nb) ? bsum[t] : 0;
    tmp[t] = v;
    __syncthreads();
    int val = v;
    for (int off = 1; off < 512; off <<= 1) {
        int add = (t >= off) ? tmp[t - off] : 0;
        __syncthreads();
        val += add;
        tmp[t] = val;
        __syncthreads();
    }
    if (t < nb) bscan[t] = val - v;    // exclusive
}

// ---------------- Kernel C3: add block offsets; finalize offs[n] = E
__global__ void scan3_kernel(int* __restrict__ offs, const int* __restrict__ bscan, int n, int E)
{
    int i = blockIdx.x * blockDim.x + threadIdx.x;
    if (i < n) offs[i] += bscan[i >> 8];
    if (i == n) offs[n] = E;
}

// ---------------- Kernel D: scatter src ids into dst-buckets
__global__ void scatter_kernel(const int* __restrict__ eidx, const int* __restrict__ offs,
                               int* __restrict__ cursor, int* __restrict__ bucket, int E)
{
    int i = blockIdx.x * blockDim.x + threadIdx.x;
    if (i < E) {
        int s = eidx[i];
        int d = eidx[E + i];
        int pos = offs[d] + atomicAdd(&cursor[d], 1);
        bucket[pos] = s;
    }
}

// ---------------- Kernel E: per-node attention + o-proj + residual + LayerNorm
__global__ __launch_bounds__(256) void attn_kernel(
    const float* __restrict__ x, const float* __restrict__ qk, const float* __restrict__ v,
    const int* __restrict__ offs, const int* __restrict__ bucket,
    const float* __restrict__ o_w, const float* __restrict__ o_b,
    const float* __restrict__ ln_g, const float* __restrict__ ln_b,
    float* __restrict__ out, int n)
{
    __shared__ float low[64 * 65];
    int tid = threadIdx.x;
    for (int i = tid; i < 64 * 64; i += 256)
        low[(i >> 6) * 65 + (i & 63)] = o_w[i];
    __syncthreads();

    int wave = tid >> 6, lane = tid & 63;
    int node = blockIdx.x * 4 + wave;
    if (node >= n) return;

    float qd = qk[node * 64 + lane];
    int beg = offs[node], end = offs[node + 1];

    float m = -1e30f, s = 0.f, acc = 0.f;
    for (int e = beg; e < end; ++e) {
        int src = bucket[e];
        float p = qd * qk[src * 64 + lane];
        #pragma unroll
        for (int w = 32; w >= 1; w >>= 1) p += __shfl_xor(p, w);
        float score = p * 0.125f;                       // / sqrt(64)
        score = fminf(5.f, fmaxf(-5.f, score));         // clamp
        float nm = fmaxf(m, score);
        float f  = __expf(m - nm);
        float pe = __expf(score - nm);
        s   = s * f + pe;
        acc = acc * f + pe * v[src * 64 + lane];
        m = nm;
    }
    float outd = (s > 0.f) ? (acc / s) : 0.f;

    // o projection: y[lane] = sum_j outd_j * o_w[lane][j] + o_b[lane]
    float y = o_b[lane];
    #pragma unroll
    for (int j = 0; j < 64; ++j) {
        float bj = __shfl(outd, j);
        y = fmaf(bj, low[lane * 65 + j], y);
    }

    float h = y + x[node * 64 + lane];
    float mean = h;
    #pragma unroll
    for (int w = 32; w >= 1; w >>= 1) mean += __shfl_xor(mean, w);
    mean *= (1.f / 64.f);
    float d0 = h - mean;
    float dv = d0 * d0;
    #pragma unroll
    for (int w = 32; w >= 1; w >>= 1) dv += __shfl_xor(dv, w);
    dv *= (1.f / 64.f);
    float r = rsqrtf(dv + LN_EPS);
    out[node * 64 + lane] = d0 * r * ln_g[lane] + ln_b[lane];
}

extern "C" void kernel_launch(void* const* d_in, const int* in_sizes, int n_in,
                              void* d_out, int out_size, void* d_ws, size_t ws_size,
                              hipStream_t stream)
{
    const float* x    = (const float*)d_in[0];
    const int*   eidx = (const int*)  d_in[1];
    const float* qk_w = (const float*)d_in[2];
    const float* qk_b = (const float*)d_in[3];
    const float* v_w  = (const float*)d_in[4];
    const float* v_b  = (const float*)d_in[5];
    const float* o_w  = (const float*)d_in[6];
    const float* o_b  = (const float*)d_in[7];
    const float* ln_g = (const float*)d_in[8];
    const float* ln_b = (const float*)d_in[9];

    const int n = in_sizes[0] / DD;      // 100000
    const int E = in_sizes[1] / 2;       // 1280000

    // workspace layout (bytes, 128-aligned)
    char* ws = (char*)d_ws;
    size_t off = 0;
    float* qk = (float*)(ws + off); off += (size_t)n * DD * 4;       // 25.6 MB
    float* v  = (float*)(ws + off); off += (size_t)n * DD * 4;       // 25.6 MB
    int* deg    = (int*)(ws + off); off += (size_t)n * 4;            // deg
    int* cursor = (int*)(ws + off); off += (size_t)n * 4;            // cursor (contiguous with deg)
    int* offs   = (int*)(ws + off); off += ((size_t)n + 32) * 4;
    int* bsum   = (int*)(ws + off); off += 2048;
    int* bscan  = (int*)(ws + off); off += 2048;
    int* bucket = (int*)(ws + off); off += (size_t)E * 4;

    const int* dst = eidx + E;

    // zero deg + cursor (contiguous) each call — ws is not re-poisoned between replays
    hipMemsetAsync(deg, 0, (size_t)2 * n * 4, stream);

    proj_kernel<<<(n + 3) / 4, 256, 0, stream>>>(x, qk_w, qk_b, v_w, v_b, qk, v, n);
    hist_kernel<<<(E + 255) / 256, 256, 0, stream>>>(dst, deg, E);

    int nb = (n + 255) / 256;            // 391 <= 512
    scan1_kernel<<<nb, 256, 0, stream>>>(deg, offs, bsum, n);
    scan2_kernel<<<1, 512, 0, stream>>>(bsum, bscan, nb);
    scan3_kernel<<<(n + 256) / 256, 256, 0, stream>>>(offs, bscan, n, E);

    scatter_kernel<<<(E + 255) / 256, 256, 0, stream>>>(eidx, offs, cursor, bucket, E);

    attn_kernel<<<(n + 3) / 4, 256, 0, stream>>>(x, qk, v, offs, bucket,
                                                 o_w, o_b, ln_g, ln_b,
                                                 (float*)d_out, n);
}

// Round 4
// 388.105 us; speedup vs baseline: 1.1919x; 1.1919x over previous
//
#include <hip/hip_runtime.h>
#include <math.h>

#define DD 64
#define LN_EPS 1e-5f

// ---------------- Kernel A: projections qk = x@qk_w^T + qk_b ; v = x@v_w^T + v_b
// 32 nodes per block (4 waves x 8 nodes) to amortize the 33KB LDS weight fill.
__global__ __launch_bounds__(256) void proj_kernel(
    const float* __restrict__ x,
    const float* __restrict__ qk_w, const float* __restrict__ qk_b,
    const float* __restrict__ v_w,  const float* __restrict__ v_b,
    float* __restrict__ qk, float* __restrict__ v, int n)
{
    __shared__ float lqw[64 * 65];
    __shared__ float lvw[64 * 65];
    int tid = threadIdx.x;
    for (int i = tid; i < 64 * 64; i += 256) {
        int r = i >> 6, c = i & 63;
        lqw[r * 65 + c] = qk_w[i];
        lvw[r * 65 + c] = v_w[i];
    }
    __syncthreads();
    int wave = tid >> 6, lane = tid & 63;
    float qb = qk_b[lane], vb = v_b[lane];
    int base = blockIdx.x * 32 + wave * 8;
    for (int k = 0; k < 8; ++k) {
        int node = base + k;
        if (node >= n) break;                    // uniform within wave
        float xv = x[node * 64 + lane];
        float aq = 0.f, av = 0.f;
        #pragma unroll
        for (int j = 0; j < 64; ++j) {
            float xb = __shfl(xv, j);            // register broadcast
            aq = fmaf(xb, lqw[lane * 65 + j], aq);
            av = fmaf(xb, lvw[lane * 65 + j], av);
        }
        qk[node * 64 + lane] = aq + qb;
        v [node * 64 + lane] = av + vb;
    }
}

// ---------------- Kernel B: in-degree histogram (4 edges/thread)
__global__ __launch_bounds__(256) void hist_kernel(const int* __restrict__ dst, int* __restrict__ deg, int E)
{
    int base = blockIdx.x * 1024 + threadIdx.x;
    #pragma unroll
    for (int k = 0; k < 4; ++k) {
        int i = base + k * 256;
        if (i < E) atomicAdd(&deg[dst[i]], 1);
    }
}

// ---------------- Kernel C1: per-block exclusive scan of deg (256 elems/block)
__global__ __launch_bounds__(256) void scan1_kernel(
    const int* __restrict__ deg, int* __restrict__ offs, int* __restrict__ bsum, int n)
{
    __shared__ int tmp[256];
    int t = threadIdx.x;
    int i = blockIdx.x * 256 + t;
    int v = (i < n) ? deg[i] : 0;
    tmp[t] = v;
    __syncthreads();
    int val = v;
    for (int off = 1; off < 256; off <<= 1) {
        int add = (t >= off) ? tmp[t - off] : 0;
        __syncthreads();
        val += add;
        tmp[t] = val;
        __syncthreads();
    }
    if (i < n) offs[i] = val - v;      // exclusive within block
    if (t == 255) bsum[blockIdx.x] = val;
}

// ---------------- Kernel C2: add per-block prefix (each block reduces bsum[0..bid-1])
__global__ __launch_bounds__(256) void scan_add_kernel(
    int* __restrict__ offs, const int* __restrict__ bsum, int n, int E)
{
    __shared__ int lsum[4];
    int bid = blockIdx.x, t = threadIdx.x;
    int v = 0;
    for (int i = t; i < bid; i += 256) v += bsum[i];
    #pragma unroll
    for (int w = 32; w >= 1; w >>= 1) v += __shfl_xor(v, w);
    if ((t & 63) == 0) lsum[t >> 6] = v;
    __syncthreads();
    int pre = lsum[0] + lsum[1] + lsum[2] + lsum[3];
    int i = bid * 256 + t;
    if (i < n) offs[i] += pre;
    if (i == n) offs[n] = E;
}

// ---------------- Kernel D: scatter src ids into dst-buckets (2 edges/thread)
__global__ __launch_bounds__(256) void scatter_kernel(
    const int* __restrict__ eidx, const int* __restrict__ offs,
    int* __restrict__ cursor, int* __restrict__ bucket, int E)
{
    int base = blockIdx.x * 512 + threadIdx.x;
    #pragma unroll
    for (int k = 0; k < 2; ++k) {
        int i = base + k * 256;
        if (i < E) {
            int s = eidx[i];
            int d = eidx[E + i];
            int pos = offs[d] + atomicAdd(&cursor[d], 1);
            bucket[pos] = s;
        }
    }
}

// ---------------- Kernel E: per-node attention + o-proj + residual + LayerNorm
// 4 waves/block = 4 nodes. Each wave: 4x16-lane subgroups, float4 per lane,
// 4 edges concurrent (x2 unroll = 8 gathers in flight). Fixed softmax shift
// m=5 (scores clamped to [-5,5]) -> no online max, merge = plain sum.
__global__ __launch_bounds__(256) void attn_kernel(
    const float* __restrict__ x, const float* __restrict__ qk, const float* __restrict__ v,
    const int* __restrict__ offs, const int* __restrict__ bucket,
    const float* __restrict__ o_w, const float* __restrict__ o_b,
    const float* __restrict__ ln_g, const float* __restrict__ ln_b,
    float* __restrict__ out, int n)
{
    __shared__ float low[64 * 65];
    __shared__ float outd_lds[4][64];
    int tid = threadIdx.x;
    for (int i = tid; i < 64 * 64; i += 256)
        low[(i >> 6) * 65 + (i & 63)] = o_w[i];
    __syncthreads();

    int wave = tid >> 6, lane = tid & 63;
    int node = blockIdx.x * 4 + wave;
    if (node >= n) return;

    int sub = lane >> 4;         // subgroup 0..3 (edge slot)
    int sl  = lane & 15;         // sublane: elems sl*4 .. sl*4+3

    const float4 q4 = *(const float4*)(qk + (size_t)node * 64 + sl * 4);
    int beg = offs[node], end = offs[node + 1];

    float s = 0.f;
    float4 acc = {0.f, 0.f, 0.f, 0.f};

    int e = beg + sub;
    // two edges per subgroup iteration (8 in flight per wave)
    for (; e + 4 < end; e += 8) {
        int s0 = bucket[e];
        int s1 = bucket[e + 4];
        const float4 k0 = *(const float4*)(qk + (size_t)s0 * 64 + sl * 4);
        const float4 k1 = *(const float4*)(qk + (size_t)s1 * 64 + sl * 4);
        const float4 v0 = *(const float4*)(v  + (size_t)s0 * 64 + sl * 4);
        const float4 v1 = *(const float4*)(v  + (size_t)s1 * 64 + sl * 4);
        float p0 = q4.x*k0.x + q4.y*k0.y + q4.z*k0.z + q4.w*k0.w;
        float p1 = q4.x*k1.x + q4.y*k1.y + q4.z*k1.z + q4.w*k1.w;
        #pragma unroll
        for (int w = 1; w <= 8; w <<= 1) { p0 += __shfl_xor(p0, w); p1 += __shfl_xor(p1, w); }
        float sc0 = fminf(5.f, fmaxf(-5.f, p0 * 0.125f));
        float sc1 = fminf(5.f, fmaxf(-5.f, p1 * 0.125f));
        float pe0 = __expf(sc0 - 5.f);
        float pe1 = __expf(sc1 - 5.f);
        s += pe0 + pe1;
        acc.x += pe0 * v0.x + pe1 * v1.x;
        acc.y += pe0 * v0.y + pe1 * v1.y;
        acc.z += pe0 * v0.z + pe1 * v1.z;
        acc.w += pe0 * v0.w + pe1 * v1.w;
    }
    if (e < end) {
        int s0 = bucket[e];
        const float4 k0 = *(const float4*)(qk + (size_t)s0 * 64 + sl * 4);
        const float4 v0 = *(const float4*)(v  + (size_t)s0 * 64 + sl * 4);
        float p0 = q4.x*k0.x + q4.y*k0.y + q4.z*k0.z + q4.w*k0.w;
        #pragma unroll
        for (int w = 1; w <= 8; w <<= 1) p0 += __shfl_xor(p0, w);
        float sc0 = fminf(5.f, fmaxf(-5.f, p0 * 0.125f));
        float pe0 = __expf(sc0 - 5.f);
        s += pe0;
        acc.x += pe0 * v0.x; acc.y += pe0 * v0.y;
        acc.z += pe0 * v0.z; acc.w += pe0 * v0.w;
    }

    // merge the 4 subgroup partials (plain sums — same shift m=5)
    s += __shfl_xor(s, 16); s += __shfl_xor(s, 32);
    acc.x += __shfl_xor(acc.x, 16); acc.x += __shfl_xor(acc.x, 32);
    acc.y += __shfl_xor(acc.y, 16); acc.y += __shfl_xor(acc.y, 32);
    acc.z += __shfl_xor(acc.z, 16); acc.z += __shfl_xor(acc.z, 32);
    acc.w += __shfl_xor(acc.w, 16); acc.w += __shfl_xor(acc.w, 32);

    float inv = (end > beg) ? (1.0f / s) : 0.f;   // s>0 iff deg>0 (pe >= e^-10)
    if (sub == 0) {
        outd_lds[wave][sl * 4 + 0] = acc.x * inv;
        outd_lds[wave][sl * 4 + 1] = acc.y * inv;
        outd_lds[wave][sl * 4 + 2] = acc.z * inv;
        outd_lds[wave][sl * 4 + 3] = acc.w * inv;
    }
    // wave-local LDS: compiler inserts lgkmcnt wait for the dependence

    // o projection: y[lane] = sum_j outd_j * o_w[lane][j] + o_b[lane]
    float y = o_b[lane];
    #pragma unroll
    for (int j = 0; j < 64; ++j)
        y = fmaf(outd_lds[wave][j], low[lane * 65 + j], y);

    float h = y + x[(size_t)node * 64 + lane];
    float mean = h;
    #pragma unroll
    for (int w = 1; w <= 32; w <<= 1) mean += __shfl_xor(mean, w);
    mean *= (1.f / 64.f);
    float d0 = h - mean;
    float dv = d0 * d0;
    #pragma unroll
    for (int w = 1; w <= 32; w <<= 1) dv += __shfl_xor(dv, w);
    dv *= (1.f / 64.f);
    float r = rsqrtf(dv + LN_EPS);
    out[(size_t)node * 64 + lane] = d0 * r * ln_g[lane] + ln_b[lane];
}

extern "C" void kernel_launch(void* const* d_in, const int* in_sizes, int n_in,
                              void* d_out, int out_size, void* d_ws, size_t ws_size,
                              hipStream_t stream)
{
    const float* x    = (const float*)d_in[0];
    const int*   eidx = (const int*)  d_in[1];
    const float* qk_w = (const float*)d_in[2];
    const float* qk_b = (const float*)d_in[3];
    const float* v_w  = (const float*)d_in[4];
    const float* v_b  = (const float*)d_in[5];
    const float* o_w  = (const float*)d_in[6];
    const float* o_b  = (const float*)d_in[7];
    const float* ln_g = (const float*)d_in[8];
    const float* ln_b = (const float*)d_in[9];

    const int n = in_sizes[0] / DD;      // 100000
    const int E = in_sizes[1] / 2;       // 1280000

    char* ws = (char*)d_ws;
    size_t off = 0;
    float* qk = (float*)(ws + off); off += (size_t)n * DD * 4;
    float* v  = (float*)(ws + off); off += (size_t)n * DD * 4;
    int* deg    = (int*)(ws + off); off += (size_t)n * 4;
    int* cursor = (int*)(ws + off); off += (size_t)n * 4;     // contiguous with deg
    int* offs   = (int*)(ws + off); off += ((size_t)n + 32) * 4;
    int* bsum   = (int*)(ws + off); off += 4096;
    int* bucket = (int*)(ws + off); off += (size_t)E * 4;

    const int* dst = eidx + E;

    hipMemsetAsync(deg, 0, (size_t)2 * n * 4, stream);

    proj_kernel<<<(n + 31) / 32, 256, 0, stream>>>(x, qk_w, qk_b, v_w, v_b, qk, v, n);
    hist_kernel<<<(E + 1023) / 1024, 256, 0, stream>>>(dst, deg, E);

    int nb = (n + 255) / 256;            // 391
    scan1_kernel<<<nb, 256, 0, stream>>>(deg, offs, bsum, n);
    scan_add_kernel<<<nb, 256, 0, stream>>>(offs, bsum, n, E);

    scatter_kernel<<<(E + 511) / 512, 256, 0, stream>>>(eidx, offs, cursor, bucket, E);

    attn_kernel<<<(n + 3) / 4, 256, 0, stream>>>(x, qk, v, offs, bucket,
                                                 o_w, o_b, ln_g, ln_b,
                                                 (float*)d_out, n);
}

// Round 5
// 253.706 us; speedup vs baseline: 1.8233x; 1.5297x over previous
//
#include <hip/hip_runtime.h>
#include <hip/hip_bf16.h>
#include <math.h>

#define DD 64
#define LN_EPS 1e-5f

__device__ __forceinline__ float bf2f(unsigned short u) {
    return __uint_as_float(((unsigned)u) << 16);
}
__device__ __forceinline__ float rlane(float v, int l) {
    return __int_as_float(__builtin_amdgcn_readlane(__float_as_int(v), l));
}

// ---------------- Kernel A: projections -> bf16.  64 nodes/block, 4 waves:
// wave0: qk nodes [0,32), wave1: qk [32,64), wave2: v [0,32), wave3: v [32,64).
// Weights live in 64 VGPRs per lane (lane = output col); x broadcast via
// v_readlane (SALU) -> zero LDS traffic in the inner loop.
__global__ __launch_bounds__(256) void proj_kernel(
    const float* __restrict__ x,
    const float* __restrict__ qk_w, const float* __restrict__ qk_b,
    const float* __restrict__ v_w,  const float* __restrict__ v_b,
    __hip_bfloat16* __restrict__ qk, __hip_bfloat16* __restrict__ v, int n)
{
    int tid = threadIdx.x;
    int wave = tid >> 6, lane = tid & 63;
    const float* W = (wave & 2) ? v_w : qk_w;
    const float* B = (wave & 2) ? v_b : qk_b;
    __hip_bfloat16* O = (wave & 2) ? v : qk;

    float w[64];
    #pragma unroll
    for (int j = 0; j < 64; ++j) w[j] = W[lane * 64 + j];
    float bias = B[lane];

    int base = blockIdx.x * 64 + (wave & 1) * 32;
    for (int k = 0; k < 32; k += 2) {
        int n0 = base + k, n1 = n0 + 1;
        if (n0 >= n) break;                          // uniform per wave
        float xv0 = x[(size_t)n0 * 64 + lane];
        float xv1 = (n1 < n) ? x[(size_t)n1 * 64 + lane] : 0.f;
        float a0 = bias, a1 = bias;
        #pragma unroll
        for (int j = 0; j < 64; ++j) {
            a0 = fmaf(rlane(xv0, j), w[j], a0);
            a1 = fmaf(rlane(xv1, j), w[j], a1);
        }
        O[(size_t)n0 * 64 + lane] = __float2bfloat16(a0);
        if (n1 < n) O[(size_t)n1 * 64 + lane] = __float2bfloat16(a1);
    }
}

// ---------------- Kernel B: in-degree histogram + per-edge rank (4 edges/thread)
__global__ __launch_bounds__(256) void hist_kernel(
    const int* __restrict__ dst, int* __restrict__ deg, int* __restrict__ rank, int E)
{
    int base = blockIdx.x * 1024 + threadIdx.x;
    #pragma unroll
    for (int k = 0; k < 4; ++k) {
        int i = base + k * 256;
        if (i < E) rank[i] = atomicAdd(&deg[dst[i]], 1);
    }
}

// ---------------- Kernel C1: per-block exclusive scan of deg (256 elems/block)
__global__ __launch_bounds__(256) void scan1_kernel(
    const int* __restrict__ deg, int* __restrict__ offs, int* __restrict__ bsum, int n)
{
    __shared__ int tmp[256];
    int t = threadIdx.x;
    int i = blockIdx.x * 256 + t;
    int v = (i < n) ? deg[i] : 0;
    tmp[t] = v;
    __syncthreads();
    int val = v;
    for (int off = 1; off < 256; off <<= 1) {
        int add = (t >= off) ? tmp[t - off] : 0;
        __syncthreads();
        val += add;
        tmp[t] = val;
        __syncthreads();
    }
    if (i < n) offs[i] = val - v;
    if (t == 255) bsum[blockIdx.x] = val;
}

// ---------------- Kernel C2: add per-block prefix
__global__ __launch_bounds__(256) void scan_add_kernel(
    int* __restrict__ offs, const int* __restrict__ bsum, int n, int E)
{
    __shared__ int lsum[4];
    int bid = blockIdx.x, t = threadIdx.x;
    int v = 0;
    for (int i = t; i < bid; i += 256) v += bsum[i];
    #pragma unroll
    for (int w = 32; w >= 1; w >>= 1) v += __shfl_xor(v, w);
    if ((t & 63) == 0) lsum[t >> 6] = v;
    __syncthreads();
    int pre = lsum[0] + lsum[1] + lsum[2] + lsum[3];
    int i = bid * 256 + t;
    if (i < n) offs[i] += pre;
    if (i == n) offs[n] = E;
}

// ---------------- Kernel D: scatter src ids (atomic-free via rank), 4 edges/thread
__global__ __launch_bounds__(256) void scatter_kernel(
    const int* __restrict__ eidx, const int* __restrict__ offs,
    const int* __restrict__ rank, int* __restrict__ bucket, int E)
{
    int base = blockIdx.x * 1024 + threadIdx.x;
    #pragma unroll
    for (int k = 0; k < 4; ++k) {
        int i = base + k * 256;
        if (i < E) bucket[offs[eidx[E + i]] + rank[i]] = eidx[i];
    }
}

// ---------------- Kernel E: per-node attention + o-proj + residual + LayerNorm
// 4 waves/block = 4 nodes. Wave = 4x16-lane subgroups, each lane holds 4 dims
// (bf16x4 = 8B/lane, 128B/row = 1 cacheline). Fixed softmax shift m=5.
__global__ __launch_bounds__(256) void attn_kernel(
    const float* __restrict__ x,
    const __hip_bfloat16* __restrict__ qk, const __hip_bfloat16* __restrict__ v,
    const int* __restrict__ offs, const int* __restrict__ bucket,
    const float* __restrict__ o_w, const float* __restrict__ o_b,
    const float* __restrict__ ln_g, const float* __restrict__ ln_b,
    float* __restrict__ out, int n)
{
    __shared__ float low[64 * 68];                 // stride 68: 16B-aligned rows
    int tid = threadIdx.x;
    for (int i = tid; i < 64 * 64; i += 256)
        low[(i >> 6) * 68 + (i & 63)] = o_w[i];
    __syncthreads();

    int wave = tid >> 6, lane = tid & 63;
    int node = blockIdx.x * 4 + wave;
    if (node >= n) return;

    int sub = lane >> 4;                           // edge slot 0..3
    int sl  = lane & 15;                           // dims sl*4 .. sl*4+3

    ushort4 qu = ((const ushort4*)(qk + (size_t)node * 64))[sl];
    float4 q4 = make_float4(bf2f(qu.x), bf2f(qu.y), bf2f(qu.z), bf2f(qu.w));
    int beg = offs[node], end = offs[node + 1];

    float s = 0.f;
    float4 acc = {0.f, 0.f, 0.f, 0.f};

    int e = beg + sub;
    for (; e + 4 < end; e += 8) {                  // 2 edges/subgroup iter
        int s0 = bucket[e];
        int s1 = bucket[e + 4];
        ushort4 k0 = ((const ushort4*)(qk + (size_t)s0 * 64))[sl];
        ushort4 k1 = ((const ushort4*)(qk + (size_t)s1 * 64))[sl];
        ushort4 u0 = ((const ushort4*)(v  + (size_t)s0 * 64))[sl];
        ushort4 u1 = ((const ushort4*)(v  + (size_t)s1 * 64))[sl];
        float p0 = q4.x*bf2f(k0.x) + q4.y*bf2f(k0.y) + q4.z*bf2f(k0.z) + q4.w*bf2f(k0.w);
        float p1 = q4.x*bf2f(k1.x) + q4.y*bf2f(k1.y) + q4.z*bf2f(k1.z) + q4.w*bf2f(k1.w);
        #pragma unroll
        for (int w = 1; w <= 8; w <<= 1) { p0 += __shfl_xor(p0, w); p1 += __shfl_xor(p1, w); }
        float sc0 = fminf(5.f, fmaxf(-5.f, p0 * 0.125f));
        float sc1 = fminf(5.f, fmaxf(-5.f, p1 * 0.125f));
        float pe0 = __expf(sc0 - 5.f);
        float pe1 = __expf(sc1 - 5.f);
        s += pe0 + pe1;
        acc.x += pe0 * bf2f(u0.x) + pe1 * bf2f(u1.x);
        acc.y += pe0 * bf2f(u0.y) + pe1 * bf2f(u1.y);
        acc.z += pe0 * bf2f(u0.z) + pe1 * bf2f(u1.z);
        acc.w += pe0 * bf2f(u0.w) + pe1 * bf2f(u1.w);
    }
    if (e < end) {
        int s0 = bucket[e];
        ushort4 k0 = ((const ushort4*)(qk + (size_t)s0 * 64))[sl];
        ushort4 u0 = ((const ushort4*)(v  + (size_t)s0 * 64))[sl];
        float p0 = q4.x*bf2f(k0.x) + q4.y*bf2f(k0.y) + q4.z*bf2f(k0.z) + q4.w*bf2f(k0.w);
        #pragma unroll
        for (int w = 1; w <= 8; w <<= 1) p0 += __shfl_xor(p0, w);
        float sc0 = fminf(5.f, fmaxf(-5.f, p0 * 0.125f));
        float pe0 = __expf(sc0 - 5.f);
        s += pe0;
        acc.x += pe0 * bf2f(u0.x); acc.y += pe0 * bf2f(u0.y);
        acc.z += pe0 * bf2f(u0.z); acc.w += pe0 * bf2f(u0.w);
    }

    // merge 4 subgroup partials (plain sums, same fixed shift) — butterfly:
    // afterwards EVERY lane holds the total for its sl's 4 dims.
    s += __shfl_xor(s, 16); s += __shfl_xor(s, 32);
    acc.x += __shfl_xor(acc.x, 16); acc.x += __shfl_xor(acc.x, 32);
    acc.y += __shfl_xor(acc.y, 16); acc.y += __shfl_xor(acc.y, 32);
    acc.z += __shfl_xor(acc.z, 16); acc.z += __shfl_xor(acc.z, 32);
    acc.w += __shfl_xor(acc.w, 16); acc.w += __shfl_xor(acc.w, 32);

    float inv = (end > beg) ? (1.0f / s) : 0.f;
    acc.x *= inv; acc.y *= inv; acc.z *= inv; acc.w *= inv;

    // o-projection: outd[4i+c] lives in lane i (and i+16/32/48) comp c ->
    // broadcast via readlane; weights via ds_read_b128 (stride-68, aligned).
    float y = o_b[lane];
    const float4* lw = (const float4*)(low + lane * 68);
    #pragma unroll
    for (int i = 0; i < 16; ++i) {
        float4 wv = lw[i];
        y = fmaf(rlane(acc.x, i), wv.x, y);
        y = fmaf(rlane(acc.y, i), wv.y, y);
        y = fmaf(rlane(acc.z, i), wv.z, y);
        y = fmaf(rlane(acc.w, i), wv.w, y);
    }

    float h = y + x[(size_t)node * 64 + lane];
    float mean = h;
    #pragma unroll
    for (int w = 1; w <= 32; w <<= 1) mean += __shfl_xor(mean, w);
    mean *= (1.f / 64.f);
    float d0 = h - mean;
    float dv = d0 * d0;
    #pragma unroll
    for (int w = 1; w <= 32; w <<= 1) dv += __shfl_xor(dv, w);
    dv *= (1.f / 64.f);
    float r = rsqrtf(dv + LN_EPS);
    out[(size_t)node * 64 + lane] = d0 * r * ln_g[lane] + ln_b[lane];
}

extern "C" void kernel_launch(void* const* d_in, const int* in_sizes, int n_in,
                              void* d_out, int out_size, void* d_ws, size_t ws_size,
                              hipStream_t stream)
{
    const float* x    = (const float*)d_in[0];
    const int*   eidx = (const int*)  d_in[1];
    const float* qk_w = (const float*)d_in[2];
    const float* qk_b = (const float*)d_in[3];
    const float* v_w  = (const float*)d_in[4];
    const float* v_b  = (const float*)d_in[5];
    const float* o_w  = (const float*)d_in[6];
    const float* o_b  = (const float*)d_in[7];
    const float* ln_g = (const float*)d_in[8];
    const float* ln_b = (const float*)d_in[9];

    const int n = in_sizes[0] / DD;      // 100000
    const int E = in_sizes[1] / 2;       // 1280000

    char* ws = (char*)d_ws;
    size_t off = 0;
    __hip_bfloat16* qk = (__hip_bfloat16*)(ws + off); off += (size_t)n * DD * 2;  // 12.8 MB
    __hip_bfloat16* v  = (__hip_bfloat16*)(ws + off); off += (size_t)n * DD * 2;  // 12.8 MB
    int* deg    = (int*)(ws + off); off += (size_t)n * 4;
    int* offs   = (int*)(ws + off); off += ((size_t)n + 32) * 4;
    int* bsum   = (int*)(ws + off); off += 4096;
    int* rank   = (int*)(ws + off); off += (size_t)E * 4;
    int* bucket = (int*)(ws + off); off += (size_t)E * 4;

    const int* dst = eidx + E;

    hipMemsetAsync(deg, 0, (size_t)n * 4, stream);

    proj_kernel<<<(n + 63) / 64, 256, 0, stream>>>(x, qk_w, qk_b, v_w, v_b, qk, v, n);
    hist_kernel<<<(E + 1023) / 1024, 256, 0, stream>>>(dst, deg, rank, E);

    int nb = (n + 255) / 256;            // 391
    scan1_kernel<<<nb, 256, 0, stream>>>(deg, offs, bsum, n);
    scan_add_kernel<<<nb, 256, 0, stream>>>(offs, bsum, n, E);

    scatter_kernel<<<(E + 1023) / 1024, 256, 0, stream>>>(eidx, offs, rank, bucket, E);

    attn_kernel<<<(n + 3) / 4, 256, 0, stream>>>(x, qk, v, offs, bucket,
                                                 o_w, o_b, ln_g, ln_b,
                                                 (float*)d_out, n);
}